// Round 10
// baseline (877.191 us; speedup 1.0000x reference)
//
#include <hip/hip_runtime.h>

#define H 512
#define MTILE 64
#define NBLK 8192
#define HPAD 520
#define STEPC (2.4f / 63.0f)

typedef _Float16 half8 __attribute__((ext_vector_type(8)));
typedef float floatx16 __attribute__((ext_vector_type(16)));

__device__ inline float silu_f(float x) {
    return __fdividef(x, 1.0f + __expf(-x));
}

// ---- prep 1: lat_part[b][j] = b0[j] + sum_d lat[b][d] * W0[d][j] ----
__global__ void prep_latw(const float* __restrict__ lat, const float* __restrict__ W0,
                          const float* __restrict__ b0, float* __restrict__ latw) {
    __shared__ float sl[H];
    const int b = blockIdx.x;
    const int j = threadIdx.x;
    sl[j] = lat[b * H + j];
    __syncthreads();
    float acc = b0[j];
#pragma unroll 8
    for (int d = 0; d < H; ++d) acc += sl[d] * W0[d * H + j];
    latw[b * H + j] = acc;
}

// ---- prep 2: W1/W2 -> fp16 for 32x32x16 MFMA B-operand ----
// k decomposed: kc=k>>5 (K=32 step), ks=(k>>4)&1 (which MFMA), hi=(k>>3)&1
// (lane half: lane>>5), j=k&7.  idx = (((l2*16+kc)*2+ks)*2+hi)*4096 + n*8 + j
// => for fixed (kc,ks,hi) 32 consecutive lanes (n) read 512 B contiguous.
__global__ void prep_w32(const float* __restrict__ W1, const float* __restrict__ W2,
                         _Float16* __restrict__ ws) {
    const int id = blockIdx.x * 512 + threadIdx.x;   // 0 .. 524287
    const int l2 = id >> 18;
    const int rem = id & 0x3FFFF;                    // k*512 + n
    const int k = rem >> 9, n = rem & 511;
    const float w = (l2 == 0 ? W1 : W2)[rem];
    const int kc = k >> 5, ks = (k >> 4) & 1, hi = (k >> 3) & 1, j = k & 7;
    ws[(size_t)((((l2 * 16 + kc) * 2 + ks) * 2 + hi)) * 4096 + n * 8 + j] = (_Float16)w;
}

// ---- main fused kernel: 32x32x16 MFMA, barrier-free K-loop, 2 blocks/CU ----
__global__ __launch_bounds__(512, 4) void mesh_main(
    const float* __restrict__ W0, const float* __restrict__ b1,
    const float* __restrict__ b2, const float* __restrict__ W3,
    const float* __restrict__ b3, const float* __restrict__ latw,
    const _Float16* __restrict__ wsB, float* __restrict__ out) {

    __shared__ _Float16 hbuf[MTILE][HPAD];        // 66.5 KB
    __shared__ float partials[8][MTILE];          // 2 KB -> 68.6 KB, 2 blocks/CU

    const int tid = threadIdx.x;
    const int wave = tid >> 6, lane = tid & 63;
    const int ln = lane & 31;                     // n / m lane index
    const int hi = lane >> 5;                     // k-half select
    const int bi = blockIdx.x;
    const int b = bi >> 12;
    const int p0 = (bi & 4095) << 6;              // 64 rows (fixed x,y; m = z)
    const float c0 = -1.2f + (float)(p0 >> 12) * STEPC;
    const float c1 = -1.2f + (float)((p0 >> 6) & 63) * STEPC;

    // ---- layer 0: h0 = silu(lat_part + coords@W0c + b0), vectorized ----
    {
        const int jg = (tid & 63) * 8;
        const int mb = (tid >> 6) * 8;
        float lw8[8], w28[8];
#pragma unroll
        for (int c = 0; c < 8; ++c) {
            const int j = jg + c;
            lw8[c] = latw[b * H + j]
                   + c0 * W0[(H + 0) * H + j]
                   + c1 * W0[(H + 1) * H + j];
            w28[c] = W0[(H + 2) * H + j];
        }
#pragma unroll
        for (int r = 0; r < 8; ++r) {
            const int m = mb + r;
            const float c2v = -1.2f + (float)m * STEPC;
            half8 hv;
#pragma unroll
            for (int c = 0; c < 8; ++c)
                hv[c] = (_Float16)silu_f(lw8[c] + c2v * w28[c]);
            *(half8*)&hbuf[m][jg] = hv;
        }
    }

    // per-lane base into B image: + hi*4096 + (col base)*8
    const _Float16* wsl = wsB + (size_t)hi * 4096 + (wave * 64 + ln) * 8;
    // per-lane base into hbuf for A fragments: row ln, k-offset hi*8
    const _Float16* arow0 = &hbuf[0][0] + ln * HPAD + hi * 8;

    floatx16 acc[2][2];    // [mf][nt] — 64 accumulator regs

    auto zero_acc = [&]() {
#pragma unroll
        for (int mf = 0; mf < 2; ++mf)
#pragma unroll
            for (int nt = 0; nt < 2; ++nt)
#pragma unroll
                for (int r = 0; r < 16; ++r) acc[mf][nt][r] = 0.f;
    };

    auto loadB = [&](int l2, int kc, half8 (&bf)[2][2]) {
        const _Float16* p = wsl + (size_t)((l2 * 16 + kc) * 2) * 8192;
#pragma unroll
        for (int ks = 0; ks < 2; ++ks)
#pragma unroll
            for (int nt = 0; nt < 2; ++nt)
                bf[ks][nt] = *(const half8*)(p + ks * 8192 + nt * 256);
    };

    auto compute = [&](int kc, half8 (&bf)[2][2]) {
        const _Float16* ar = arow0 + kc * 32;
        half8 a[2][2];
#pragma unroll
        for (int mf = 0; mf < 2; ++mf)
#pragma unroll
            for (int ks = 0; ks < 2; ++ks)
                a[mf][ks] = *(const half8*)(ar + mf * 32 * HPAD + ks * 16);
#pragma unroll
        for (int ks = 0; ks < 2; ++ks)
#pragma unroll
            for (int nt = 0; nt < 2; ++nt)
#pragma unroll
                for (int mf = 0; mf < 2; ++mf)
                    acc[mf][nt] = __builtin_amdgcn_mfma_f32_32x32x16_f16(
                        a[mf][ks], bf[ks][nt], acc[mf][nt], 0, 0, 0);
    };

    // depth-1 prefetch, two named buffers, consume-before-overwrite
    auto run_gemm = [&](int l2) {
        half8 B0[2][2], B1[2][2];
        loadB(l2, 0, B0);
#pragma unroll 1
        for (int kc = 0; kc < 16; kc += 2) {
            loadB(l2, kc + 1, B1);
            compute(kc, B0);
            loadB(l2, (kc + 2) & 15, B0);  // wraps to 0 on last iter: harmless
            compute(kc + 1, B1);
        }
    };

    // ---- GEMM 1 ----
    zero_acc();
    __syncthreads();             // h0 ready
    run_gemm(0);
    __syncthreads();             // all waves done reading h0
    // writeback h1 = silu(acc + b1); C/D map: row=(r&3)+8*(r>>2)+4*hi, col=ln
    {
        float b1v[2];
#pragma unroll
        for (int nt = 0; nt < 2; ++nt) b1v[nt] = b1[wave * 64 + nt * 32 + ln];
#pragma unroll
        for (int mf = 0; mf < 2; ++mf)
#pragma unroll
            for (int nt = 0; nt < 2; ++nt)
#pragma unroll
                for (int r = 0; r < 16; ++r) {
                    const int m = mf * 32 + (r & 3) + 8 * (r >> 2) + 4 * hi;
                    const int col = wave * 64 + nt * 32 + ln;
                    hbuf[m][col] = (_Float16)silu_f(acc[mf][nt][r] + b1v[nt]);
                }
    }

    // ---- GEMM 2 ----
    zero_acc();
    __syncthreads();             // h1 ready
    run_gemm(1);

    // ---- final layer: out = silu(acc + b2) @ W3 + b3 ----
    {
        float b2v[2], w3v[2];
#pragma unroll
        for (int nt = 0; nt < 2; ++nt) {
            const int col = wave * 64 + nt * 32 + ln;
            b2v[nt] = b2[col];
            w3v[nt] = W3[col];
        }
#pragma unroll
        for (int mf = 0; mf < 2; ++mf)
#pragma unroll
            for (int r = 0; r < 16; ++r) {
                float sum = 0.f;
#pragma unroll
                for (int nt = 0; nt < 2; ++nt)
                    sum += silu_f(acc[mf][nt][r] + b2v[nt]) * w3v[nt];
                // reduce across the 32 col-lanes (stays within lane&31 group)
                sum += __shfl_xor(sum, 1);
                sum += __shfl_xor(sum, 2);
                sum += __shfl_xor(sum, 4);
                sum += __shfl_xor(sum, 8);
                sum += __shfl_xor(sum, 16);
                if (ln == 0) {
                    const int m = mf * 32 + (r & 3) + 8 * (r >> 2) + 4 * hi;
                    partials[wave][m] = sum;
                }
            }
    }
    __syncthreads();
    if (tid < MTILE) {
        float o = b3[0];
#pragma unroll
        for (int w = 0; w < 8; ++w) o += partials[w][tid];
        out[(size_t)bi * MTILE + tid] = o;
    }
}

extern "C" void kernel_launch(void* const* d_in, const int* in_sizes, int n_in,
                              void* d_out, int out_size, void* d_ws, size_t ws_size,
                              hipStream_t stream) {
    const float* lat = (const float*)d_in[0];
    const float* W0  = (const float*)d_in[1];
    const float* b0  = (const float*)d_in[2];
    const float* W1  = (const float*)d_in[3];
    const float* b1  = (const float*)d_in[4];
    const float* W2  = (const float*)d_in[5];
    const float* b2  = (const float*)d_in[6];
    const float* W3  = (const float*)d_in[7];
    const float* b3  = (const float*)d_in[8];
    float* out = (float*)d_out;

    float* latw = (float*)d_ws;                               // 4 KB
    _Float16* wsB = (_Float16*)((char*)d_ws + 4096);          // 1 MB

    prep_latw<<<2, 512, 0, stream>>>(lat, W0, b0, latw);
    prep_w32<<<1024, 512, 0, stream>>>(W1, W2, wsB);
    mesh_main<<<NBLK, 512, 0, stream>>>(W0, b1, b2, W3, b3, latw, wsB, out);
}